// Round 9
// baseline (76.222 us; speedup 1.0000x reference)
//
#include <hip/hip_runtime.h>
#include <hip/hip_bf16.h>

#define B 32
#define T 8192
#define H 128

typedef __attribute__((ext_vector_type(8)))  short short8_t;   // 8 bf16 = 4 VGPR
typedef __attribute__((ext_vector_type(16))) float f32x16;     // MFMA 32x32 acc
typedef __attribute__((ext_vector_type(4)))  float f32x4;

static __device__ __forceinline__ unsigned fbits(float x) { return __builtin_bit_cast(unsigned, x); }
static __device__ __forceinline__ float bfloat(unsigned u) { return __builtin_bit_cast(float, u); }

// ws layout: [0,16K) u fp32 ; [16K,80K) W2 hi|lo frags bf16
#define WPK_OFF  16384

// ---------------------------------------------------------------------------
// Kernel 1 (merged prep): blocks 0..31 -> u[b][h]; blocks 32..39 -> pack W2.
// ---------------------------------------------------------------------------
__global__ void k_prep(const float* __restrict__ hidden,
                       const float* __restrict__ W_attn,
                       const float* __restrict__ b_attn,
                       float* __restrict__ u,
                       unsigned short* __restrict__ wpk) {
    const int tid = threadIdx.x;
    if (blockIdx.x < 32) {
        const int b = blockIdx.x;
        __shared__ float hrow[H];
        if (tid < H) hrow[tid] = hidden[b * H + tid];
        __syncthreads();
        if (tid < H) {
            const float* w = W_attn + (size_t)tid * (2 * H);
            float acc = b_attn[tid];
#pragma unroll
            for (int k = 0; k < H; ++k) acc = fmaf(w[k], hrow[k], acc);
            u[b * H + tid] = acc;
        }
    } else {
        const int idx  = (blockIdx.x - 32) * 256 + tid;   // 0..2047
        const int s    = idx >> 8;
        const int m    = (idx >> 6) & 3;
        const int lane = idx & 63;
        const int h    = m * 32 + (lane & 31);
        const int k0   = s * 16 + (lane >> 5) * 8;
        const float* src = W_attn + (size_t)h * (2 * H) + H + k0;
        const int base = ((s * 4 + m) * 64 + lane) * 8;
#pragma unroll
        for (int e = 0; e < 8; ++e) {
            const float x = src[e];
            const unsigned ux = fbits(x);
            const unsigned hb = ux & 0xffff0000u;         // truncated bf16 hi
            const float r = x - bfloat(hb);               // exact remainder
            wpk[base + e]         = (unsigned short)(ux >> 16);
            wpk[16384 + base + e] = (unsigned short)(fbits(r) >> 16);
        }
    }
}

// ---------------------------------------------------------------------------
// Kernel 2: scores via MFMA with COALESCED LDS-staged enc + 1-deep prefetch.
//
// Old path: lane reads its own row -> 32 strided 64B lines per instruction
// (2x line-transactions) -> ~3 TB/s effective. New path: per round a block
// stages 4 contiguous t-groups (64 KB contiguous) with thread i loading
// float4 #(w*512+i) -> perfect coalescing; regs -> swizzled ds_write;
// next round's loads are issued BEFORE compute so HBM drain hides (T14).
//
// LDS enc layout: row (0..127) x 32 16B-units, unit d stored at
// du = (d + row) & 31 (rotation; both write and read sides -> bank-uniform).
// Read for (s,kh,j): du = (4s + 2kh + j + l31) & 31.
//
// Proven constraints kept: acc = 2 x f32x16 per wave; in-loop barriers
// (3/round) as scheduling fences. launch_bounds(512,2): reg cap 256 (LDS
// already limits to 1 block/CU = 2 waves/SIMD) so stg[8] + u-frags fit.
// ---------------------------------------------------------------------------
__global__ __launch_bounds__(512, 2) void k_scores_mfma(
    const float* __restrict__ enc,                 // [T*B][H]
    const float* __restrict__ u,                   // [B][H]
    const float* __restrict__ v,                   // [H]
    const unsigned short* __restrict__ wpk,        // 64 KB frag-ordered hi|lo
    float* __restrict__ scores)                    // [B][T]
{
    __shared__ unsigned short wlds[32768];         // 64 KB W2 frags
    __shared__ float4 ebuf4[4096];                 // 64 KB enc tile (swizzled)
    __shared__ float pairbuf[4][32];

    const int tid  = threadIdx.x;
    const int lane = tid & 63;
    const int wid  = tid >> 6;      // 0..7
    const int pair = wid >> 1;      // 0..3 : which t of the round
    const int mh   = wid & 1;       // h-half: tiles {2mh, 2mh+1}
    const int l31  = lane & 31;
    const int kh   = lane >> 5;
    const int mt0  = mh * 2;
    const int mt1  = mh * 2 + 1;

    // one-time stage of packed W2 frags
    {
        const float4* src = (const float4*)wpk;
        float4* dst = (float4*)wlds;
#pragma unroll
        for (int i = 0; i < 8; ++i) dst[tid + i * 512] = src[tid + i * 512];
    }

    // hoisted round-invariant u fragments (C-init) — 32 VGPRs
    float4 uf0[4], uf1[4];
#pragma unroll
    for (int r4 = 0; r4 < 4; ++r4) {
        uf0[r4] = *(const float4*)(u + l31 * H + mt0 * 32 + r4 * 8 + kh * 4);
        uf1[r4] = *(const float4*)(u + l31 * H + mt1 * 32 + r4 * 8 + kh * 4);
    }

    const int t0 = blockIdx.x * 32;         // 8 rounds x 4 t per block

    // prologue: load round-0 tile into regs (coalesced)
    float4 stg[8];
    {
        const float4* gs = (const float4*)(enc + (size_t)t0 * 32 * H);
#pragma unroll
        for (int w = 0; w < 8; ++w) stg[w] = gs[w * 512 + tid];
    }

    // read-side constants
    const int ebase = pair * 1024 + l31 * 32;   // float4 index of own row
    const int roff  = 2 * kh + l31;             // rotation + kh unit offset

    __syncthreads();   // wlds ready

    for (int q = 0; q < 8; ++q) {
        // ---- write staged tile to LDS (swizzled rotation) ----
#pragma unroll
        for (int w = 0; w < 8; ++w) {
            const int U   = w * 512 + tid;
            const int row = U >> 5;
            const int du  = ((U & 31) + row) & 31;
            ebuf4[row * 32 + du] = stg[w];
        }
        __syncthreads();                        // tile q visible

        // ---- issue next round's loads (drain hides under compute) ----
        if (q < 7) {
            const float4* gs = (const float4*)(enc + (size_t)(t0 + 4 * (q + 1)) * 32 * H);
#pragma unroll
            for (int w = 0; w < 8; ++w) stg[w] = gs[w * 512 + tid];
        }

        // ---- compute own t ----
        const int g = t0 + 4 * q + pair;        // t index

        f32x16 acc0, acc1;
#pragma unroll
        for (int r4 = 0; r4 < 4; ++r4) {
            acc0[4 * r4 + 0] = uf0[r4].x; acc0[4 * r4 + 1] = uf0[r4].y;
            acc0[4 * r4 + 2] = uf0[r4].z; acc0[4 * r4 + 3] = uf0[r4].w;
            acc1[4 * r4 + 0] = uf1[r4].x; acc1[4 * r4 + 1] = uf1[r4].y;
            acc1[4 * r4 + 2] = uf1[r4].z; acc1[4 * r4 + 3] = uf1[r4].w;
        }

#pragma unroll
        for (int s = 0; s < 8; ++s) {
            const int ia = (4 * s + roff) & 31;
            const int ib = (4 * s + 1 + roff) & 31;
            const float4 xa = ebuf4[ebase + ia];
            const float4 xb = ebuf4[ebase + ib];
            const float xv[8] = {xa.x, xa.y, xa.z, xa.w, xb.x, xb.y, xb.z, xb.w};

            union { short8_t v8; unsigned w[4]; } bhi, blo;
#pragma unroll
            for (int p2 = 0; p2 < 4; ++p2) {
                const float x0 = xv[2 * p2], x1 = xv[2 * p2 + 1];
                const unsigned u0 = fbits(x0), u1 = fbits(x1);
                const unsigned h0 = u0 & 0xffff0000u, h1 = u1 & 0xffff0000u;
                const float r0 = x0 - bfloat(h0), r1 = x1 - bfloat(h1);
                bhi.w[p2] = (u0 >> 16) | h1;
                blo.w[p2] = (fbits(r0) >> 16) | (fbits(r1) & 0xffff0000u);
            }

            {
                const int fo0 = ((s * 4 + mt0) * 64 + lane) * 8;  // ushort idx
                const short8_t ahi = *(const short8_t*)(wlds + fo0);
                const short8_t alo = *(const short8_t*)(wlds + 16384 + fo0);
                acc0 = __builtin_amdgcn_mfma_f32_32x32x16_bf16(ahi, bhi.v8, acc0, 0, 0, 0);
                acc0 = __builtin_amdgcn_mfma_f32_32x32x16_bf16(alo, bhi.v8, acc0, 0, 0, 0);
                acc0 = __builtin_amdgcn_mfma_f32_32x32x16_bf16(ahi, blo.v8, acc0, 0, 0, 0);
            }
            {
                const int fo1 = ((s * 4 + mt1) * 64 + lane) * 8;
                const short8_t ahi = *(const short8_t*)(wlds + fo1);
                const short8_t alo = *(const short8_t*)(wlds + 16384 + fo1);
                acc1 = __builtin_amdgcn_mfma_f32_32x32x16_bf16(ahi, bhi.v8, acc1, 0, 0, 0);
                acc1 = __builtin_amdgcn_mfma_f32_32x32x16_bf16(alo, bhi.v8, acc1, 0, 0, 0);
                acc1 = __builtin_amdgcn_mfma_f32_32x32x16_bf16(ahi, blo.v8, acc1, 0, 0, 0);
            }
        }

        // ---- epilogue: partial score over this wave's 64 h-rows ----
        float psum = 0.f;
#pragma unroll
        for (int r4 = 0; r4 < 4; ++r4) {
            const float4 v0 = *(const float4*)(v + mt0 * 32 + r4 * 8 + kh * 4);
            const float4 v1 = *(const float4*)(v + mt1 * 32 + r4 * 8 + kh * 4);
            psum = fmaf(fmaxf(acc0[4 * r4 + 0], 0.f), v0.x, psum);
            psum = fmaf(fmaxf(acc0[4 * r4 + 1], 0.f), v0.y, psum);
            psum = fmaf(fmaxf(acc0[4 * r4 + 2], 0.f), v0.z, psum);
            psum = fmaf(fmaxf(acc0[4 * r4 + 3], 0.f), v0.w, psum);
            psum = fmaf(fmaxf(acc1[4 * r4 + 0], 0.f), v1.x, psum);
            psum = fmaf(fmaxf(acc1[4 * r4 + 1], 0.f), v1.y, psum);
            psum = fmaf(fmaxf(acc1[4 * r4 + 2], 0.f), v1.z, psum);
            psum = fmaf(fmaxf(acc1[4 * r4 + 3], 0.f), v1.w, psum);
        }
        psum += __shfl_xor(psum, 32);   // collapse kh halves; lanes<32 hold b

        // ---- pair combine via LDS (barriers double as fences) ----
        if (mh == 0 && lane < 32) pairbuf[pair][l31] = psum;
        __syncthreads();
        if (mh == 1 && lane < 32)
            scores[(size_t)l31 * T + g] = psum + pairbuf[pair][l31];
        __syncthreads();                // guards pairbuf AND ebuf reuse
    }
}

// ---------------------------------------------------------------------------
// Kernel 3: ragged masked softmax per b, row in registers (1R + 1W).
// ---------------------------------------------------------------------------
#define SM_TPB 1024
#define SM_PER (T / SM_TPB)

__global__ __launch_bounds__(SM_TPB) void k_softmax(
    float* __restrict__ out, const int* __restrict__ len_seq)
{
    const int b    = blockIdx.x;
    const int tid  = threadIdx.x;
    const int lane = tid & 63;
    const int wid  = tid >> 6;
    const int len  = len_seq[b];
    float* s = out + (size_t)b * T;

    __shared__ float red[16];

    float val[SM_PER];
#pragma unroll
    for (int i = 0; i < SM_PER; ++i) val[i] = s[tid + i * SM_TPB];

    float m = -1e30f;
#pragma unroll
    for (int i = 0; i < SM_PER; ++i)
        if (tid + i * SM_TPB < len) m = fmaxf(m, val[i]);
#pragma unroll
    for (int off = 32; off >= 1; off >>= 1) m = fmaxf(m, __shfl_xor(m, off));
    if (lane == 0) red[wid] = m;
    __syncthreads();
    if (wid == 0) {
        float xv = (lane < 16) ? red[lane] : -1e30f;
#pragma unroll
        for (int off = 8; off >= 1; off >>= 1) xv = fmaxf(xv, __shfl_xor(xv, off));
        if (lane == 0) red[0] = xv;
    }
    __syncthreads();
    m = red[0];
    __syncthreads();

    float sum = 0.0f;
#pragma unroll
    for (int i = 0; i < SM_PER; ++i) {
        const int t = tid + i * SM_TPB;
        val[i] = (t < len) ? __expf(val[i] - m) : 0.0f;
        sum += val[i];
    }
#pragma unroll
    for (int off = 32; off >= 1; off >>= 1) sum += __shfl_xor(sum, off);
    if (lane == 0) red[wid] = sum;
    __syncthreads();
    if (wid == 0) {
        float xv = (lane < 16) ? red[lane] : 0.f;
#pragma unroll
        for (int off = 8; off >= 1; off >>= 1) xv += __shfl_xor(xv, off);
        if (lane == 0) red[0] = xv;
    }
    __syncthreads();
    const float inv = 1.0f / red[0];

#pragma unroll
    for (int i = 0; i < SM_PER; ++i) s[tid + i * SM_TPB] = val[i] * inv;
}

// ---------------------------------------------------------------------------
extern "C" void kernel_launch(void* const* d_in, const int* in_sizes, int n_in,
                              void* d_out, int out_size, void* d_ws, size_t ws_size,
                              hipStream_t stream) {
    const float* hidden = (const float*)d_in[0];
    const float* enc    = (const float*)d_in[1];
    const int*   len    = (const int*)d_in[2];
    const float* W      = (const float*)d_in[3];
    const float* bb     = (const float*)d_in[4];
    const float* v      = (const float*)d_in[5];

    float* out  = (float*)d_out;
    float* u_ws = (float*)d_ws;                                     // 16 KB
    unsigned short* wpk = (unsigned short*)((char*)d_ws + WPK_OFF); // 64 KB

    k_prep<<<40, 256, 0, stream>>>(hidden, W, bb, u_ws, wpk);
    k_scores_mfma<<<256, 512, 0, stream>>>(enc, u_ws, v, wpk, out);
    k_softmax<<<B, SM_TPB, 0, stream>>>(out, len);
}

// Round 10
// 53.251 us; speedup vs baseline: 1.4314x; 1.4314x over previous
//
#include <hip/hip_runtime.h>
#include <hip/hip_bf16.h>

#define B 32
#define T 8192
#define H 128

typedef __attribute__((ext_vector_type(8)))  short short8_t;   // 8 bf16 = 4 VGPR
typedef __attribute__((ext_vector_type(16))) float f32x16;     // MFMA 32x32 acc

static __device__ __forceinline__ unsigned fbits(float x) { return __builtin_bit_cast(unsigned, x); }
static __device__ __forceinline__ float bfloat(unsigned u) { return __builtin_bit_cast(float, u); }

// direct global->LDS DMA, 16 B per lane. LDS dest = wave-uniform base +
// lane*16 (HW); global src is per-lane.
static __device__ __forceinline__ void gload16(const float4* g, float4* l) {
    __builtin_amdgcn_global_load_lds(
        (const __attribute__((address_space(1))) unsigned int*)g,
        (__attribute__((address_space(3))) unsigned int*)l,
        16, 0, 0);
}

// ws layout: [0,16K) u fp32 ; [16K,80K) W2 hi|lo frags bf16
#define WPK_OFF  16384

// ---------------------------------------------------------------------------
// Kernel 1 (merged prep): blocks 0..31 -> u[b][h]; blocks 32..39 -> pack W2.
// ---------------------------------------------------------------------------
__global__ void k_prep(const float* __restrict__ hidden,
                       const float* __restrict__ W_attn,
                       const float* __restrict__ b_attn,
                       float* __restrict__ u,
                       unsigned short* __restrict__ wpk) {
    const int tid = threadIdx.x;
    if (blockIdx.x < 32) {
        const int b = blockIdx.x;
        __shared__ float hrow[H];
        if (tid < H) hrow[tid] = hidden[b * H + tid];
        __syncthreads();
        if (tid < H) {
            const float* w = W_attn + (size_t)tid * (2 * H);
            float acc = b_attn[tid];
#pragma unroll
            for (int k = 0; k < H; ++k) acc = fmaf(w[k], hrow[k], acc);
            u[b * H + tid] = acc;
        }
    } else {
        const int idx  = (blockIdx.x - 32) * 256 + tid;   // 0..2047
        const int s    = idx >> 8;
        const int m    = (idx >> 6) & 3;
        const int lane = idx & 63;
        const int h    = m * 32 + (lane & 31);
        const int k0   = s * 16 + (lane >> 5) * 8;
        const float* src = W_attn + (size_t)h * (2 * H) + H + k0;
        const int base = ((s * 4 + m) * 64 + lane) * 8;
#pragma unroll
        for (int e = 0; e < 8; ++e) {
            const float x = src[e];
            const unsigned ux = fbits(x);
            const unsigned hb = ux & 0xffff0000u;         // truncated bf16 hi
            const float r = x - bfloat(hb);               // exact remainder
            wpk[base + e]         = (unsigned short)(ux >> 16);
            wpk[16384 + base + e] = (unsigned short)(fbits(r) >> 16);
        }
    }
}

// ---------------------------------------------------------------------------
// Kernel 2: scores via MFMA, enc staged via global_load_lds (zero-register
// transport — round 9's reg-staged version spilled 132 MB of scratch).
//
// Per round a block stages 4 contiguous t-groups (128 rows x 512 B = 64 KB
// contiguous enc). Wave w fills rows [16w,16w+16): 8 instructions, each
// covering 2 rows (64 lanes x 16 B, contiguous LDS -> conflict-free write).
// Swizzle (rule #21, both-sides): LDS is LINEAR [row][slot]; slot j of row r
// receives global unit (j - r) & 31 (inverse rotation on the SOURCE addr);
// reader fetches unit d at slot (d + r) & 31. Validated conflict-free in r9.
//
// Proven constraints kept: acc = 2 x f32x16/wave; in-loop barriers as
// scheduling fences; u-fragments hoisted.
// ---------------------------------------------------------------------------
__global__ __launch_bounds__(512, 2) void k_scores_mfma(
    const float* __restrict__ enc,                 // [T*B][H]
    const float* __restrict__ u,                   // [B][H]
    const float* __restrict__ v,                   // [H]
    const unsigned short* __restrict__ wpk,        // 64 KB frag-ordered hi|lo
    float* __restrict__ scores)                    // [B][T]
{
    __shared__ unsigned short wlds[32768];         // 64 KB W2 frags
    __shared__ float4 ebuf4[4096];                 // 64 KB enc tile (linear)
    __shared__ float pairbuf[4][32];

    const int tid  = threadIdx.x;
    const int lane = tid & 63;
    const int wid  = tid >> 6;      // 0..7
    const int pair = wid >> 1;      // 0..3 : which t of the round
    const int mh   = wid & 1;       // h-half: tiles {2mh, 2mh+1}
    const int l31  = lane & 31;
    const int kh   = lane >> 5;
    const int mt0  = mh * 2;
    const int mt1  = mh * 2 + 1;

    // one-time stage of packed W2 frags
    {
        const float4* src = (const float4*)wpk;
        float4* dst = (float4*)wlds;
#pragma unroll
        for (int i = 0; i < 8; ++i) dst[tid + i * 512] = src[tid + i * 512];
    }

    // hoisted round-invariant u fragments (C-init) — 32 VGPRs
    float4 uf0[4], uf1[4];
#pragma unroll
    for (int r4 = 0; r4 < 4; ++r4) {
        uf0[r4] = *(const float4*)(u + l31 * H + mt0 * 32 + r4 * 8 + kh * 4);
        uf1[r4] = *(const float4*)(u + l31 * H + mt1 * 32 + r4 * 8 + kh * 4);
    }

    const int t0 = blockIdx.x * 32;             // 8 rounds x 4 t per block
    const float4* enc4 = (const float4*)enc;    // 32 units per row

    // read-side constants
    const int ebase = pair * 1024 + l31 * 32;   // float4 index of own row
    const int roff  = 2 * kh + l31;             // rotation + kh unit offset

    __syncthreads();   // wlds ready

    for (int q = 0; q < 8; ++q) {
        // ---- stage tile q: global -> LDS DMA, swizzled source ----
        {
            const size_t brow = (size_t)(t0 + 4 * q) * 32;   // global row base
#pragma unroll
            for (int i = 0; i < 8; ++i) {
                const int rl = wid * 16 + 2 * i + kh;        // tile row 0..127
                const int gu = (l31 - rl) & 31;              // inverse rotation
                gload16(enc4 + (brow + rl) * 32 + gu,
                        &ebuf4[(wid * 16 + 2 * i) * 32]);    // uniform base
            }
        }
        __syncthreads();                        // vmcnt drain: tile q visible

        // ---- compute own t ----
        const int g = t0 + 4 * q + pair;        // t index

        f32x16 acc0, acc1;
#pragma unroll
        for (int r4 = 0; r4 < 4; ++r4) {
            acc0[4 * r4 + 0] = uf0[r4].x; acc0[4 * r4 + 1] = uf0[r4].y;
            acc0[4 * r4 + 2] = uf0[r4].z; acc0[4 * r4 + 3] = uf0[r4].w;
            acc1[4 * r4 + 0] = uf1[r4].x; acc1[4 * r4 + 1] = uf1[r4].y;
            acc1[4 * r4 + 2] = uf1[r4].z; acc1[4 * r4 + 3] = uf1[r4].w;
        }

#pragma unroll
        for (int s = 0; s < 8; ++s) {
            const int ia = (4 * s + roff) & 31;
            const int ib = (4 * s + 1 + roff) & 31;
            const float4 xa = ebuf4[ebase + ia];
            const float4 xb = ebuf4[ebase + ib];
            const float xv[8] = {xa.x, xa.y, xa.z, xa.w, xb.x, xb.y, xb.z, xb.w};

            union { short8_t v8; unsigned w[4]; } bhi, blo;
#pragma unroll
            for (int p2 = 0; p2 < 4; ++p2) {
                const float x0 = xv[2 * p2], x1 = xv[2 * p2 + 1];
                const unsigned u0 = fbits(x0), u1 = fbits(x1);
                const unsigned h0 = u0 & 0xffff0000u, h1 = u1 & 0xffff0000u;
                const float r0 = x0 - bfloat(h0), r1 = x1 - bfloat(h1);
                bhi.w[p2] = (u0 >> 16) | h1;
                blo.w[p2] = (fbits(r0) >> 16) | (fbits(r1) & 0xffff0000u);
            }

            {
                const int fo0 = ((s * 4 + mt0) * 64 + lane) * 8;  // ushort idx
                const short8_t ahi = *(const short8_t*)(wlds + fo0);
                const short8_t alo = *(const short8_t*)(wlds + 16384 + fo0);
                acc0 = __builtin_amdgcn_mfma_f32_32x32x16_bf16(ahi, bhi.v8, acc0, 0, 0, 0);
                acc0 = __builtin_amdgcn_mfma_f32_32x32x16_bf16(alo, bhi.v8, acc0, 0, 0, 0);
                acc0 = __builtin_amdgcn_mfma_f32_32x32x16_bf16(ahi, blo.v8, acc0, 0, 0, 0);
            }
            {
                const int fo1 = ((s * 4 + mt1) * 64 + lane) * 8;
                const short8_t ahi = *(const short8_t*)(wlds + fo1);
                const short8_t alo = *(const short8_t*)(wlds + 16384 + fo1);
                acc1 = __builtin_amdgcn_mfma_f32_32x32x16_bf16(ahi, bhi.v8, acc1, 0, 0, 0);
                acc1 = __builtin_amdgcn_mfma_f32_32x32x16_bf16(alo, bhi.v8, acc1, 0, 0, 0);
                acc1 = __builtin_amdgcn_mfma_f32_32x32x16_bf16(ahi, blo.v8, acc1, 0, 0, 0);
            }
        }

        // ---- epilogue: partial score over this wave's 64 h-rows ----
        float psum = 0.f;
#pragma unroll
        for (int r4 = 0; r4 < 4; ++r4) {
            const float4 v0 = *(const float4*)(v + mt0 * 32 + r4 * 8 + kh * 4);
            const float4 v1 = *(const float4*)(v + mt1 * 32 + r4 * 8 + kh * 4);
            psum = fmaf(fmaxf(acc0[4 * r4 + 0], 0.f), v0.x, psum);
            psum = fmaf(fmaxf(acc0[4 * r4 + 1], 0.f), v0.y, psum);
            psum = fmaf(fmaxf(acc0[4 * r4 + 2], 0.f), v0.z, psum);
            psum = fmaf(fmaxf(acc0[4 * r4 + 3], 0.f), v0.w, psum);
            psum = fmaf(fmaxf(acc1[4 * r4 + 0], 0.f), v1.x, psum);
            psum = fmaf(fmaxf(acc1[4 * r4 + 1], 0.f), v1.y, psum);
            psum = fmaf(fmaxf(acc1[4 * r4 + 2], 0.f), v1.z, psum);
            psum = fmaf(fmaxf(acc1[4 * r4 + 3], 0.f), v1.w, psum);
        }
        psum += __shfl_xor(psum, 32);   // collapse kh halves; lanes<32 hold b

        // ---- pair combine via LDS (barriers double as fences) ----
        if (mh == 0 && lane < 32) pairbuf[pair][l31] = psum;
        __syncthreads();
        if (mh == 1 && lane < 32)
            scores[(size_t)l31 * T + g] = psum + pairbuf[pair][l31];
        __syncthreads();                // guards pairbuf AND ebuf reuse
    }
}

// ---------------------------------------------------------------------------
// Kernel 3: ragged masked softmax per b, row in registers (1R + 1W).
// ---------------------------------------------------------------------------
#define SM_TPB 1024
#define SM_PER (T / SM_TPB)

__global__ __launch_bounds__(SM_TPB) void k_softmax(
    float* __restrict__ out, const int* __restrict__ len_seq)
{
    const int b    = blockIdx.x;
    const int tid  = threadIdx.x;
    const int lane = tid & 63;
    const int wid  = tid >> 6;
    const int len  = len_seq[b];
    float* s = out + (size_t)b * T;

    __shared__ float red[16];

    float val[SM_PER];
#pragma unroll
    for (int i = 0; i < SM_PER; ++i) val[i] = s[tid + i * SM_TPB];

    float m = -1e30f;
#pragma unroll
    for (int i = 0; i < SM_PER; ++i)
        if (tid + i * SM_TPB < len) m = fmaxf(m, val[i]);
#pragma unroll
    for (int off = 32; off >= 1; off >>= 1) m = fmaxf(m, __shfl_xor(m, off));
    if (lane == 0) red[wid] = m;
    __syncthreads();
    if (wid == 0) {
        float xv = (lane < 16) ? red[lane] : -1e30f;
#pragma unroll
        for (int off = 8; off >= 1; off >>= 1) xv = fmaxf(xv, __shfl_xor(xv, off));
        if (lane == 0) red[0] = xv;
    }
    __syncthreads();
    m = red[0];
    __syncthreads();

    float sum = 0.0f;
#pragma unroll
    for (int i = 0; i < SM_PER; ++i) {
        const int t = tid + i * SM_TPB;
        val[i] = (t < len) ? __expf(val[i] - m) : 0.0f;
        sum += val[i];
    }
#pragma unroll
    for (int off = 32; off >= 1; off >>= 1) sum += __shfl_xor(sum, off);
    if (lane == 0) red[wid] = sum;
    __syncthreads();
    if (wid == 0) {
        float xv = (lane < 16) ? red[lane] : 0.f;
#pragma unroll
        for (int off = 8; off >= 1; off >>= 1) xv += __shfl_xor(xv, off);
        if (lane == 0) red[0] = xv;
    }
    __syncthreads();
    const float inv = 1.0f / red[0];

#pragma unroll
    for (int i = 0; i < SM_PER; ++i) s[tid + i * SM_TPB] = val[i] * inv;
}

// ---------------------------------------------------------------------------
extern "C" void kernel_launch(void* const* d_in, const int* in_sizes, int n_in,
                              void* d_out, int out_size, void* d_ws, size_t ws_size,
                              hipStream_t stream) {
    const float* hidden = (const float*)d_in[0];
    const float* enc    = (const float*)d_in[1];
    const int*   len    = (const int*)d_in[2];
    const float* W      = (const float*)d_in[3];
    const float* bb     = (const float*)d_in[4];
    const float* v      = (const float*)d_in[5];

    float* out  = (float*)d_out;
    float* u_ws = (float*)d_ws;                                     // 16 KB
    unsigned short* wpk = (unsigned short*)((char*)d_ws + WPK_OFF); // 64 KB

    k_prep<<<40, 256, 0, stream>>>(hidden, W, bb, u_ws, wpk);
    k_scores_mfma<<<256, 512, 0, stream>>>(enc, u_ws, v, wpk, out);
    k_softmax<<<B, SM_TPB, 0, stream>>>(out, len);
}